// Round 8
// baseline (539.423 us; speedup 1.0000x reference)
//
#include <hip/hip_runtime.h>
#include <hip/hip_cooperative_groups.h>
#include <math.h>

namespace cg = cooperative_groups;

#define N_NODES 10000
#define N_EDGES 160000
#define N_FEAT  512
#define HEADS   8
#define HID     128

typedef __attribute__((ext_vector_type(8))) short bf16x8;
typedef __attribute__((ext_vector_type(4))) float f32x4;
typedef __attribute__((ext_vector_type(2))) float v2f;

// ---------------------------------------------------------------------------
// fp32 <-> bf16 helpers
// ---------------------------------------------------------------------------
__device__ inline unsigned short f2bf_rne(float f) {
  unsigned int u = __float_as_uint(f);
  unsigned int r = u + 0x7fffu + ((u >> 16) & 1u);
  return (unsigned short)(r >> 16);
}
__device__ inline float bf2f(unsigned int b) {
  return __uint_as_float(b << 16);
}

// ---------------------------------------------------------------------------
// split body: fp32 [R][K] -> bf16 in MFMA-fragment-major layout (hi only).
// ---------------------------------------------------------------------------
__device__ inline void split_body(const float* __restrict__ in,
                                  unsigned short* __restrict__ hi,
                                  int R, int K8, int idx) {
  int r = idx & 15;
  int t = idx >> 4;
  int kq = t % K8;
  int rb = t / K8;
  int row = rb * 16 + r;
  float v[8] = {0.f, 0.f, 0.f, 0.f, 0.f, 0.f, 0.f, 0.f};
  if (row < R) {
    const float* p = in + (size_t)row * (K8 * 8) + kq * 8;
    float4 a = *(const float4*)p;
    float4 b = *(const float4*)(p + 4);
    v[0] = a.x; v[1] = a.y; v[2] = a.z; v[3] = a.w;
    v[4] = b.x; v[5] = b.y; v[6] = b.z; v[7] = b.w;
  }
  union { unsigned short u[8]; int4 v4; } H;
  #pragma unroll
  for (int e = 0; e < 8; ++e) H.u[e] = f2bf_rne(v[e]);
  *(int4*)&hi[(size_t)idx * 8] = H.v4;
}

// ---------------------------------------------------------------------------
// 8-wave (4x2) 128x128 bf16 MFMA tile, BK=64.  Per-wave: 2x4 output frags
// (32 acc VGPR), 12 loads + 16 MFMA per K-step — fits the 128-VGPR cap that
// the cooperative 2-blocks/CU co-residency requires.
// ---------------------------------------------------------------------------
__device__ inline void gemm_tile_8w(const bf16x8* __restrict__ pA,
                                    const bf16x8* __restrict__ pB,
                                    unsigned short* __restrict__ hb,
                                    int M, int K, int tile, int tid) {
  int wave = tid >> 6, lane = tid & 63;
  int r = lane & 15, q = lane >> 4;
  int wr = wave >> 1, wc = wave & 1;          // 4 x 2 wave grid
  int mtile = tile % 80;
  int head = tile / 80;
  int m0 = mtile * 128;
  int K8 = K >> 3;
  size_t rstep = (size_t)K8 * 16;
  size_t aidx = (size_t)((m0 >> 4) + wr * 2) * rstep + (size_t)q * 16 + r;
  size_t bidx = (size_t)(head * 8 + wc * 4) * rstep + (size_t)q * 16 + r;

  f32x4 acc[2][4] = {};

  for (int k0 = 0; k0 < K; k0 += 64, aidx += 128, bidx += 128) {
    bf16x8 a[4], b[8];
    #pragma unroll
    for (int i = 0; i < 2; ++i) {
      a[i]     = pA[aidx + i * rstep];
      a[i + 2] = pA[aidx + i * rstep + 64];
    }
    #pragma unroll
    for (int j = 0; j < 4; ++j) {
      b[j]     = pB[bidx + j * rstep];
      b[j + 4] = pB[bidx + j * rstep + 64];
    }
    #pragma unroll
    for (int i = 0; i < 2; ++i)
      #pragma unroll
      for (int j = 0; j < 4; ++j)
        acc[i][j] = __builtin_amdgcn_mfma_f32_16x16x32_bf16(a[i], b[j], acc[i][j], 0, 0, 0);
    #pragma unroll
    for (int i = 0; i < 2; ++i)
      #pragma unroll
      for (int j = 0; j < 4; ++j)
        acc[i][j] = __builtin_amdgcn_mfma_f32_16x16x32_bf16(a[i + 2], b[j + 4], acc[i][j], 0, 0, 0);
  }

  #pragma unroll
  for (int i = 0; i < 2; ++i)
    #pragma unroll
    for (int reg = 0; reg < 4; ++reg) {
      int row = m0 + wr * 32 + i * 16 + q * 4 + reg;
      if (row < M) {
        #pragma unroll
        for (int j = 0; j < 4; ++j)
          hb[((size_t)head * M + row) * HID + wc * 64 + j * 16 + r] =
              f2bf_rne(acc[i][j][reg]);
      }
    }
}

// ---------------------------------------------------------------------------
// Softmax + aggregation phase (bucket CSR), grid-stride.  One wave = 4 dst of
// one head; 8 waves/block.  Wave-synchronous LDS staging; 8 gathers in flight.
// ---------------------------------------------------------------------------
__device__ inline void agg_phase(const unsigned short* __restrict__ hb,
                                 const float* __restrict__ si,
                                 const float* __restrict__ sj,
                                 const int* __restrict__ deg,
                                 const int* __restrict__ slots,
                                 const int2* __restrict__ ovf,
                                 const int* __restrict__ cnt,
                                 unsigned short* __restrict__ aggb,
                                 char* smem, int tid, int bid, int nblk) {
  int2 (*prs)[4][32] = (int2 (*)[4][32])smem;     // [8 waves][4 grp][32]
  int wv = tid >> 6;
  int lane = tid & 63;
  int grp = lane >> 4;
  int sl = lane & 15;
  for (int vb = bid; vb < 313 * 8; vb += nblk) {
    int head = vb & 7;
    int n = (vb >> 3) * 32 + wv * 4 + grp;
    const unsigned short* hbase = hb + (size_t)head * N_NODES * HID;
    const float* sjh = sj + (size_t)head * N_NODES;
    bool nv = n < N_NODES;
    int dg = 0;
    float s_i = 0.f;
    if (nv) {
      dg = deg[n];
      s_i = si[(size_t)head * N_NODES + n];
    }
    int sbase = n * 32;

    int src0 = 0, src1 = 0;
    float sc0 = -INFINITY, sc1 = -INFINITY;
    if (sl < dg) {
      src0 = slots[sbase + sl];
      float t = s_i + sjh[src0];
      sc0 = t > 0.f ? t : 0.01f * t;
    }
    if (16 + sl < dg) {
      src1 = slots[sbase + 16 + sl];
      float t = s_i + sjh[src1];
      sc1 = t > 0.f ? t : 0.01f * t;
    }
    float m = fmaxf(sc0, sc1);
    int oc = 0;
    if (dg > 32) {
      oc = cnt[1];
      if (oc > N_EDGES) oc = N_EDGES;
      for (int e2 = sl; e2 < oc; e2 += 16) {
        int2 pe = ovf[e2];
        if (pe.x == n) {
          float t = s_i + sjh[pe.y];
          t = t > 0.f ? t : 0.01f * t;
          m = fmaxf(m, t);
        }
      }
    }
    #pragma unroll
    for (int o = 1; o <= 8; o <<= 1) m = fmaxf(m, __shfl_xor(m, o));

    float w0 = (sl < dg) ? __expf(sc0 - m) : 0.f;
    float w1 = (16 + sl < dg) ? __expf(sc1 - m) : 0.f;
    float den = w0 + w1;
    if (dg > 32) {
      for (int e2 = sl; e2 < oc; e2 += 16) {
        int2 pe = ovf[e2];
        if (pe.x == n) {
          float t = s_i + sjh[pe.y];
          t = t > 0.f ? t : 0.01f * t;
          den += __expf(t - m);
        }
      }
    }
    #pragma unroll
    for (int o = 1; o <= 8; o <<= 1) den += __shfl_xor(den, o);

    prs[wv][grp][sl] = make_int2(src0, __float_as_int(w0));
    prs[wv][grp][16 + sl] = make_int2(src1, __float_as_int(w1));
    __asm__ volatile("s_waitcnt lgkmcnt(0)" ::: "memory");

    v2f a01 = {0.f, 0.f}, a23 = {0.f, 0.f}, a45 = {0.f, 0.f}, a67 = {0.f, 0.f};
    int dmin = dg < 32 ? dg : 32;
    for (int e0 = 0; e0 < dmin; e0 += 8) {
      int2 p[8];
      #pragma unroll
      for (int u = 0; u < 8; ++u) p[u] = prs[wv][grp][e0 + u];
      int4 pv[8];
      #pragma unroll
      for (int u = 0; u < 8; ++u)
        pv[u] = *(const int4*)&hbase[(size_t)p[u].x * HID + sl * 8];
      #pragma unroll
      for (int u = 0; u < 8; ++u) {
        float w = __int_as_float(p[u].y);
        v2f w2 = {w, w};
        int4 q = pv[u];
        v2f t0 = {bf2f((unsigned)q.x & 0xffffu), __uint_as_float((unsigned)q.x & 0xffff0000u)};
        v2f t1 = {bf2f((unsigned)q.y & 0xffffu), __uint_as_float((unsigned)q.y & 0xffff0000u)};
        v2f t2 = {bf2f((unsigned)q.z & 0xffffu), __uint_as_float((unsigned)q.z & 0xffff0000u)};
        v2f t3 = {bf2f((unsigned)q.w & 0xffffu), __uint_as_float((unsigned)q.w & 0xffff0000u)};
        a01 += w2 * t0;
        a23 += w2 * t1;
        a45 += w2 * t2;
        a67 += w2 * t3;
      }
    }
    if (dg > 32) {
      for (int e2 = 0; e2 < oc; ++e2) {
        int2 pe = ovf[e2];
        if (pe.x != n) continue;
        float t = s_i + sjh[pe.y];
        t = t > 0.f ? t : 0.01f * t;
        float w = __expf(t - m);
        v2f w2 = {w, w};
        int4 q = *(const int4*)&hbase[(size_t)pe.y * HID + sl * 8];
        v2f t0 = {bf2f((unsigned)q.x & 0xffffu), __uint_as_float((unsigned)q.x & 0xffff0000u)};
        v2f t1 = {bf2f((unsigned)q.y & 0xffffu), __uint_as_float((unsigned)q.y & 0xffff0000u)};
        v2f t2 = {bf2f((unsigned)q.z & 0xffffu), __uint_as_float((unsigned)q.z & 0xffff0000u)};
        v2f t3 = {bf2f((unsigned)q.w & 0xffffu), __uint_as_float((unsigned)q.w & 0xffff0000u)};
        a01 += w2 * t0; a23 += w2 * t1; a45 += w2 * t2; a67 += w2 * t3;
      }
    }

    if (nv) {
      float inv = den > 0.f ? 1.0f / den : 0.f;
      union { unsigned short u[8]; int4 v4; } P;
      P.u[0] = f2bf_rne(a01.x * inv); P.u[1] = f2bf_rne(a01.y * inv);
      P.u[2] = f2bf_rne(a23.x * inv); P.u[3] = f2bf_rne(a23.y * inv);
      P.u[4] = f2bf_rne(a45.x * inv); P.u[5] = f2bf_rne(a45.y * inv);
      P.u[6] = f2bf_rne(a67.x * inv); P.u[7] = f2bf_rne(a67.y * inv);
      *(int4*)&aggb[((size_t)head * N_NODES + n) * HID + sl * 8] = P.v4;
    }
  }
}

// ---------------------------------------------------------------------------
// THE pipeline: one cooperative dispatch, 7 grid syncs replace 7 dispatch
// boundaries (~10us each).  512 thr/block, VGPR<=128, 43KB LDS arena ->
// 2 blocks/CU co-resident at grid<=512 (runtime-clamped).
// ---------------------------------------------------------------------------
__global__ __launch_bounds__(512, 4)
void fused_gat(const float* __restrict__ x, const int* __restrict__ esrc,
               const int* __restrict__ edst,
               const float* __restrict__ W1, const float* __restrict__ a1,
               const float* __restrict__ W2, const float* __restrict__ a2,
               const float* __restrict__ ln_g, const float* __restrict__ ln_b,
               const float* __restrict__ Wl1, const float* __restrict__ bl1,
               const float* __restrict__ Wl2, const float* __restrict__ bl2,
               const float* __restrict__ Wl3, const float* __restrict__ bl3,
               float* __restrict__ out,
               unsigned short* __restrict__ aggb, float* __restrict__ si,
               float* __restrict__ sj, float* __restrict__ g,
               int* __restrict__ deg, int* __restrict__ cnt,
               int* __restrict__ slots, int2* __restrict__ ovf,
               float* __restrict__ wt1, float* __restrict__ wt2,
               unsigned short* __restrict__ Afh, unsigned short* __restrict__ Bfh,
               unsigned short* __restrict__ Bfh2, unsigned short* __restrict__ hb) {
  __shared__ __align__(16) char smem[43264];
  cg::grid_group grid = cg::this_grid();
  const int tid = threadIdx.x;
  const int bid = blockIdx.x;
  const int nblk = gridDim.x;
  const int gtid = bid * 512 + tid;
  const int gstride = nblk * 512;

  // ================= P0: splits + bucket CSR + w-tilde =================
  for (int idx = gtid; idx < 640 * 64 * 16; idx += gstride)
    split_body(x, Afh, N_NODES, 64, idx);
  for (int idx = gtid; idx < 64 * 64 * 16; idx += gstride)
    split_body(W1, Bfh, HEADS * HID, 64, idx);
  for (int idx = gtid; idx < 64 * 16 * 16; idx += gstride)
    split_body(W2, Bfh2, HEADS * HID, 16, idx);
  for (int e = gtid; e < N_EDGES; e += gstride) {
    int d = edst[e], s = esrc[e];
    int p = atomicAdd(&deg[d], 1);
    if (p < 32) {
      slots[d * 32 + p] = s;
    } else {
      int q = atomicAdd(&cnt[1], 1);
      if (q < N_EDGES) ovf[q] = make_int2(d, s);
    }
  }
  for (int o = gtid; o < 8192; o += gstride) {       // wt1
    int f = o & 511, ii = (o >> 9) & 1, h = o >> 10;
    const float* Wp = W1 + (size_t)h * HID * N_FEAT + f;
    const float* ap = a1 + h * 2 * HID + ii * HID;
    float c0 = 0.f, c1 = 0.f;
    for (int d = 0; d < HID; d += 2) {
      c0 = fmaf(Wp[(size_t)d * N_FEAT], ap[d], c0);
      c1 = fmaf(Wp[(size_t)(d + 1) * N_FEAT], ap[d + 1], c1);
    }
    wt1[o] = c0 + c1;
  }
  for (int o = gtid; o < 2048; o += gstride) {       // wt2
    int f = o & 127, ii = (o >> 7) & 1, h = o >> 8;
    const float* Wp = W2 + (size_t)h * HID * HID + f;
    const float* ap = a2 + h * 2 * HID + ii * HID;
    float c0 = 0.f, c1 = 0.f;
    for (int d = 0; d < HID; d += 2) {
      c0 = fmaf(Wp[(size_t)d * HID], ap[d], c0);
      c1 = fmaf(Wp[(size_t)(d + 1) * HID], ap[d + 1], c1);
    }
    wt2[o] = c0 + c1;
  }
  grid.sync();

  // ================= P1: gemm L1 + layer-1 score GEMV =================
  for (int t = bid; t < 640; t += nblk)
    gemm_tile_8w((const bf16x8*)Afh, (const bf16x8*)Bfh, hb, N_NODES, N_FEAT, t, tid);
  {
    float* wl = (float*)smem;                        // 32 KB wt1 table
    for (int k = tid; k < 8192; k += 512) wl[k] = wt1[k];
    __syncthreads();
    int wv = tid >> 6, lane = tid & 63;
    int rr = lane >> 4, sl = lane & 15;
    for (int vb = bid; vb < 313; vb += nblk) {
      int n = vb * 32 + wv * 4 + rr;
      float acc[16];
      #pragma unroll
      for (int t = 0; t < 16; ++t) acc[t] = 0.f;
      if (n < N_NODES) {
        const float* xp = x + (size_t)n * N_FEAT + sl * 4;
        #pragma unroll
        for (int k = 0; k < 8; ++k) {
          float4 xv = *(const float4*)(xp + k * 64);
          #pragma unroll
          for (int t = 0; t < 16; ++t) {
            float4 w4 = *(const float4*)&wl[t * 512 + k * 64 + sl * 4];
            acc[t] = fmaf(xv.x, w4.x, fmaf(xv.y, w4.y, fmaf(xv.z, w4.z, fmaf(xv.w, w4.w, acc[t]))));
          }
        }
      }
      #pragma unroll
      for (int o = 1; o <= 8; o <<= 1)
        #pragma unroll
        for (int t = 0; t < 16; ++t) acc[t] += __shfl_xor(acc[t], o);
      if (n < N_NODES) {
        float outv = acc[0];
        #pragma unroll
        for (int t = 1; t < 16; ++t) outv = (sl == t) ? acc[t] : outv;
        int h = sl >> 1;
        if (sl & 1) sj[(size_t)h * N_NODES + n] = outv;
        else        si[(size_t)h * N_NODES + n] = outv;
      }
    }
  }
  grid.sync();

  // ================= P2: aggregate L1 =================
  agg_phase(hb, si, sj, deg, slots, ovf, cnt, aggb, smem, tid, bid, nblk);
  grid.sync();

  // ================= P3: head-mean + ELU -> A frags + layer-2 scores =======
  {
    float* wl2 = (float*)smem;                                   // 8 KB
    float (*sred)[32][17] = (float (*)[32][17])(smem + 8192);    // 34.8 KB
    for (int k = tid; k < 2048; k += 512) wl2[k] = wt2[k];
    __syncthreads();
    int kq = tid >> 5, r32 = tid & 31;
    for (int vb = bid; vb < 313; vb += nblk) {
      int n = vb * 32 + r32;
      float s[8] = {0.f, 0.f, 0.f, 0.f, 0.f, 0.f, 0.f, 0.f};
      if (n < N_NODES) {
        #pragma unroll
        for (int hh = 0; hh < HEADS; ++hh) {
          int4 pv = *(const int4*)&aggb[((size_t)hh * N_NODES + n) * HID + kq * 8];
          s[0] += bf2f((unsigned)pv.x & 0xffffu);
          s[1] += __uint_as_float((unsigned)pv.x & 0xffff0000u);
          s[2] += bf2f((unsigned)pv.y & 0xffffu);
          s[3] += __uint_as_float((unsigned)pv.y & 0xffff0000u);
          s[4] += bf2f((unsigned)pv.z & 0xffffu);
          s[5] += __uint_as_float((unsigned)pv.z & 0xffff0000u);
          s[6] += bf2f((unsigned)pv.w & 0xffffu);
          s[7] += __uint_as_float((unsigned)pv.w & 0xffff0000u);
        }
      }
      float p[16];
      #pragma unroll
      for (int t = 0; t < 16; ++t) p[t] = 0.f;
      union { unsigned short u[8]; int4 v4; } H;
      #pragma unroll
      for (int e = 0; e < 8; ++e) {
        float v = s[e] * (1.0f / HEADS);
        v = v > 0.f ? v : (__expf(v) - 1.0f);        // ELU
        #pragma unroll
        for (int t = 0; t < 16; ++t) p[t] = fmaf(v, wl2[t * 128 + kq * 8 + e], p[t]);
        H.u[e] = f2bf_rne(v);
      }
      if (n < N_NODES) {
        size_t idx = ((size_t)(n >> 4) * 16 + kq) * 16 + (n & 15);  // K8=16 frag
        *(int4*)&Afh[idx * 8] = H.v4;
      }
      #pragma unroll
      for (int t = 0; t < 16; ++t) sred[kq][r32][t] = p[t];
      __syncthreads();
      {
        int rr = tid >> 4, t = tid & 15;             // 32 rows x 16 targets
        float sum = 0.f;
        #pragma unroll
        for (int k = 0; k < 16; ++k) sum += sred[k][rr][t];
        int nn = vb * 32 + rr;
        if (nn < N_NODES) {
          int h = t >> 1;
          if (t & 1) sj[(size_t)h * N_NODES + nn] = sum;
          else       si[(size_t)h * N_NODES + nn] = sum;
        }
      }
      __syncthreads();
    }
  }
  grid.sync();

  // ================= P4: gemm L2 =================
  for (int t = bid; t < 640; t += nblk)
    gemm_tile_8w((const bf16x8*)Afh, (const bf16x8*)Bfh2, hb, N_NODES, HID, t, tid);
  grid.sync();

  // ================= P5: aggregate L2 =================
  agg_phase(hb, si, sj, deg, slots, ovf, cnt, aggb, smem, tid, bid, nblk);
  grid.sync();

  // ================= P6: head-mean + ELU + pooling =================
  {
    float (*sm)[128] = (float (*)[128])smem;         // 16 KB
    int nl = tid >> 4, dgx = tid & 15;
    for (int vb = bid; vb < 313; vb += nblk) {
      int n = vb * 32 + nl;
      float v[8] = {0.f, 0.f, 0.f, 0.f, 0.f, 0.f, 0.f, 0.f};
      if (n < N_NODES) {
        #pragma unroll
        for (int hh = 0; hh < HEADS; ++hh) {
          int4 pv = *(const int4*)&aggb[((size_t)hh * N_NODES + n) * HID + dgx * 8];
          v[0] += bf2f((unsigned)pv.x & 0xffffu);
          v[1] += __uint_as_float((unsigned)pv.x & 0xffff0000u);
          v[2] += bf2f((unsigned)pv.y & 0xffffu);
          v[3] += __uint_as_float((unsigned)pv.y & 0xffff0000u);
          v[4] += bf2f((unsigned)pv.z & 0xffffu);
          v[5] += __uint_as_float((unsigned)pv.z & 0xffff0000u);
          v[6] += bf2f((unsigned)pv.w & 0xffffu);
          v[7] += __uint_as_float((unsigned)pv.w & 0xffff0000u);
        }
        #pragma unroll
        for (int e = 0; e < 8; ++e) {
          float xv = v[e] * (1.0f / HEADS);
          v[e] = xv > 0.f ? xv : (__expf(xv) - 1.0f);  // ELU
        }
      }
      #pragma unroll
      for (int e = 0; e < 8; ++e) sm[nl][dgx * 8 + e] = v[e];
      __syncthreads();
      if (tid < 128) {
        float s = 0.f;
        #pragma unroll
        for (int nn = 0; nn < 32; ++nn) s += sm[nn][tid];
        atomicAdd(&g[tid], s);
      }
      __syncthreads();
    }
  }
  grid.sync();

  // ================= P7: LayerNorm + MLP head (block 0) =================
  if (bid == 0) {
    float* red = (float*)smem;
    float* gnb = red + 128;
    float* x1 = gnb + 128;
    float* x2 = x1 + 64;
    int t = tid;
    float gg = 0.f;
    if (t < 128) {
      gg = g[t] * (1.0f / N_NODES);
      red[t] = gg;
    }
    __syncthreads();
    for (int o = 64; o > 0; o >>= 1) {
      if (t < o) red[t] += red[t + o];
      __syncthreads();
    }
    float mu = red[0] * (1.0f / HID);
    __syncthreads();
    if (t < 128) red[t] = (gg - mu) * (gg - mu);
    __syncthreads();
    for (int o = 64; o > 0; o >>= 1) {
      if (t < o) red[t] += red[t + o];
      __syncthreads();
    }
    float var = red[0] * (1.0f / HID);
    __syncthreads();
    if (t < 128) gnb[t] = (gg - mu) / sqrtf(var + 1e-5f) * ln_g[t] + ln_b[t];
    __syncthreads();
    if (t < 64) {
      float s = bl1[t];
      for (int k = 0; k < 128; ++k) s += Wl1[t * 128 + k] * gnb[k];
      x1[t] = s > 0.f ? s : 0.01f * s;
    }
    __syncthreads();
    if (t < 16) {
      float s = bl2[t];
      for (int k = 0; k < 64; ++k) s += Wl2[t * 64 + k] * x1[k];
      x2[t] = s > 0.f ? s : 0.01f * s;
    }
    __syncthreads();
    if (t < 16) {
      float s = bl3[t];
      for (int k = 0; k < 16; ++k) s += Wl3[t * 16 + k] * x2[k];
      out[t] = s > 0.f ? s : 0.f;
    }
  }
}

// ---------------------------------------------------------------------------
extern "C" void kernel_launch(void* const* d_in, const int* in_sizes, int n_in,
                              void* d_out, int out_size, void* d_ws, size_t ws_size,
                              hipStream_t stream) {
  const float* x    = (const float*)d_in[0];
  const int*   esrc = (const int*)d_in[1];
  const int*   edst = (const int*)d_in[2];
  const float* W1   = (const float*)d_in[3];
  const float* a1   = (const float*)d_in[4];
  const float* W2   = (const float*)d_in[5];
  const float* a2   = (const float*)d_in[6];
  const float* ln_g = (const float*)d_in[7];
  const float* ln_b = (const float*)d_in[8];
  const float* Wl1  = (const float*)d_in[9];
  const float* bl1  = (const float*)d_in[10];
  const float* Wl2  = (const float*)d_in[11];
  const float* bl2  = (const float*)d_in[12];
  const float* Wl3  = (const float*)d_in[13];
  const float* bl3  = (const float*)d_in[14];
  float* out = (float*)d_out;

  const int RBPAD = 640;

  // workspace carve-up (g, deg, cnt contiguous -> one memset)
  unsigned short* aggb = (unsigned short*)d_ws;                 // 20.5 MB
  float* si   = (float*)(aggb + (size_t)N_NODES * HEADS * HID); // 80,000
  float* sj   = si + N_NODES * HEADS;                           // 80,000
  float* g    = sj + N_NODES * HEADS;                           // 128
  int*   deg  = (int*)(g + 128);                                // 10,000
  int*   cnt  = deg + N_NODES;                                  // 4
  int*   slots= cnt + 4;                                        // 320,000
  int2*  ovf  = (int2*)(slots + (size_t)N_NODES * 32);          // worst-case E
  float* wt1  = (float*)(ovf + N_EDGES);                        // 8192
  float* wt2  = wt1 + 8192;                                     // 2048
  unsigned short* Afh  = (unsigned short*)(wt2 + 2048);         // 10.5 MB
  unsigned short* Bfh  = Afh + (size_t)RBPAD * 64 * 128;        // 1 MB
  unsigned short* Bfh2 = Bfh + (size_t)1024 * 512;              // 256 KB
  unsigned short* hb   = Bfh2 + (size_t)1024 * 128;             // 20.5 MB

  hipMemsetAsync(g, 0, 128 * sizeof(float) + (N_NODES + 4) * sizeof(int), stream);

  int maxB = 0;
  if (hipOccupancyMaxActiveBlocksPerMultiprocessor(&maxB, fused_gat, 512, 0)
          != hipSuccess || maxB < 1)
    maxB = 1;
  int gridSz = (maxB >= 2) ? 512 : 256;

  void* args[] = {
    (void*)&x, (void*)&esrc, (void*)&edst, (void*)&W1, (void*)&a1,
    (void*)&W2, (void*)&a2, (void*)&ln_g, (void*)&ln_b,
    (void*)&Wl1, (void*)&bl1, (void*)&Wl2, (void*)&bl2,
    (void*)&Wl3, (void*)&bl3, (void*)&out,
    (void*)&aggb, (void*)&si, (void*)&sj, (void*)&g,
    (void*)&deg, (void*)&cnt, (void*)&slots, (void*)&ovf,
    (void*)&wt1, (void*)&wt2, (void*)&Afh, (void*)&Bfh,
    (void*)&Bfh2, (void*)&hb
  };
  hipLaunchCooperativeKernel((const void*)fused_gat, dim3(gridSz), dim3(512),
                             args, 0, stream);
}

// Round 9
// 271.488 us; speedup vs baseline: 1.9869x; 1.9869x over previous
//
#include <hip/hip_runtime.h>
#include <math.h>

#define N_NODES 10000
#define N_EDGES 160000
#define N_FEAT  512
#define HEADS   8
#define HID     128

typedef __attribute__((ext_vector_type(8))) short bf16x8;
typedef __attribute__((ext_vector_type(4))) float f32x4;
typedef __attribute__((ext_vector_type(2))) float v2f;

// ---------------------------------------------------------------------------
// fp32 <-> bf16 helpers
// ---------------------------------------------------------------------------
__device__ inline unsigned short f2bf_rne(float f) {
  unsigned int u = __float_as_uint(f);
  unsigned int r = u + 0x7fffu + ((u >> 16) & 1u);
  return (unsigned short)(r >> 16);
}
__device__ inline float bf2f(unsigned int b) {
  return __uint_as_float(b << 16);
}

// ---------------------------------------------------------------------------
// split body: fp32 [R][K] -> bf16 in MFMA-fragment-major layout (hi only).
// ---------------------------------------------------------------------------
__device__ inline void split_body(const float* __restrict__ in,
                                  unsigned short* __restrict__ hi,
                                  int R, int K8, int idx) {
  int r = idx & 15;
  int t = idx >> 4;
  int kq = t % K8;
  int rb = t / K8;
  int row = rb * 16 + r;
  float v[8] = {0.f, 0.f, 0.f, 0.f, 0.f, 0.f, 0.f, 0.f};
  if (row < R) {
    const float* p = in + (size_t)row * (K8 * 8) + kq * 8;
    float4 a = *(const float4*)p;
    float4 b = *(const float4*)(p + 4);
    v[0] = a.x; v[1] = a.y; v[2] = a.z; v[3] = a.w;
    v[4] = b.x; v[5] = b.y; v[6] = b.z; v[7] = b.w;
  }
  union { unsigned short u[8]; int4 v4; } H;
  #pragma unroll
  for (int e = 0; e < 8; ++e) H.u[e] = f2bf_rne(v[e]);
  *(int4*)&hi[(size_t)idx * 8] = H.v4;
}

// ---------------------------------------------------------------------------
// ONE dispatch: A split + W1 split + W2 split + bucket-CSR build + w-tilde.
// Bucket CSR: slots[n][32] via atomicAdd(deg); overflow edges to a BOUNDED
// (dst,src) list scanned by the aggregate's rare tail (R6 hardening — the
// unbounded write was the probable container-killer).
// ---------------------------------------------------------------------------
__global__ __launch_bounds__(256)
void split_frag2(const float* __restrict__ in1, unsigned short* __restrict__ hi1,
                 int R1, int K81, int total1, int nb1,
                 const float* __restrict__ in2, unsigned short* __restrict__ hi2,
                 int R2, int K82, int total2, int nb2,
                 const float* __restrict__ W2p, unsigned short* __restrict__ hi3,
                 int total3, int nb3,
                 const int* __restrict__ esrc, const int* __restrict__ edst,
                 int* __restrict__ deg, int* __restrict__ slots,
                 int2* __restrict__ ovf, int* __restrict__ cnt, int E,
                 const float* __restrict__ av1, const float* __restrict__ av2,
                 float* __restrict__ wt1, float* __restrict__ wt2) {
  int b = (int)blockIdx.x;
  int tid = threadIdx.x;
  if (b < nb1) {
    int idx = b * 256 + tid;
    if (idx < total1) split_body(in1, hi1, R1, K81, idx);
  } else if (b < nb1 + nb2) {
    int idx = (b - nb1) * 256 + tid;
    if (idx < total2) split_body(in2, hi2, R2, K82, idx);
  } else if (b < nb1 + nb2 + nb3) {
    int idx = (b - nb1 - nb2) * 256 + tid;
    if (idx < total3) split_body(W2p, hi3, HEADS * HID, 16, idx);
  } else {
    int nbE = (E + 255) / 256;
    int eb = b - nb1 - nb2 - nb3;
    if (eb < nbE) {
      int e = eb * 256 + tid;
      if (e < E) {
        int d = edst[e], s = esrc[e];
        int p = atomicAdd(&deg[d], 1);
        if (p < 32) {
          slots[d * 32 + p] = s;
        } else {
          int q = atomicAdd(&cnt[1], 1);
          if (q < E) ovf[q] = make_int2(d, s);   // bounded (defensive)
        }
      }
    } else {
      int wb = eb - nbE;
      if (wb < 32) {                      // wt1: 8192 outputs, 128-dots over W1
        int o = wb * 256 + tid;
        int f = o & 511, ii = (o >> 9) & 1, h = o >> 10;
        const float* Wp = in2 + (size_t)h * HID * N_FEAT + f;   // in2 == W1
        const float* ap = av1 + h * 2 * HID + ii * HID;
        float c0 = 0.f, c1 = 0.f;
        for (int d = 0; d < HID; d += 2) {
          c0 = fmaf(Wp[(size_t)d * N_FEAT], ap[d], c0);
          c1 = fmaf(Wp[(size_t)(d + 1) * N_FEAT], ap[d + 1], c1);
        }
        wt1[o] = c0 + c1;
      } else {                            // wt2: 2048 outputs over W2
        int o = (wb - 32) * 256 + tid;
        int f = o & 127, ii = (o >> 7) & 1, h = o >> 8;
        const float* Wp = W2p + (size_t)h * HID * HID + f;
        const float* ap = av2 + h * 2 * HID + ii * HID;
        float c0 = 0.f, c1 = 0.f;
        for (int d = 0; d < HID; d += 2) {
          c0 = fmaf(Wp[(size_t)d * HID], ap[d], c0);
          c1 = fmaf(Wp[(size_t)(d + 1) * HID], ap[d + 1], c1);
        }
        wt2[o] = c0 + c1;
      }
    }
  }
}

// ---------------------------------------------------------------------------
// Pure-bf16 MFMA GEMM (128x128 tile, 2x2 waves) + FUSED layer-1 score GEMV.
// R9: BK=128 (K=512 -> 4 iterations).  Gemm law from R2/R3: time ~ number of
// load-latency exposures, not per-iter work — halving iterations again.
// 32 operand regs + 16 acc ~ 210 VGPR -> launch_bounds(256,2) (R8 lesson:
// starving the allocator spills; give it the 256-VGPR budget).
// ---------------------------------------------------------------------------
__global__ __launch_bounds__(256, 2)
void gemm_score(const unsigned short* __restrict__ Afh,
                const unsigned short* __restrict__ Bfh,
                unsigned short* __restrict__ hb,
                int M, int K, int nbGemm,
                const float* __restrict__ x, const float* __restrict__ wt1,
                float* __restrict__ si, float* __restrict__ sj, int N) {
  int tid = threadIdx.x;
  if ((int)blockIdx.x >= nbGemm) {
    // ---- score blocks: 16 rows each; wave = 4 rows x 16 lanes ----
    __shared__ float wl[8192];            // wt1 [16 t][512 f], 32 KB
    #pragma unroll
    for (int k = 0; k < 32; ++k) wl[tid + k * 256] = wt1[tid + k * 256];
    __syncthreads();
    int wv = tid >> 6, lane = tid & 63;
    int rr = lane >> 4, sl = lane & 15;
    int n = ((int)blockIdx.x - nbGemm) * 16 + wv * 4 + rr;
    if (n >= N) return;
    const float* xp = x + (size_t)n * N_FEAT + sl * 4;
    float acc[16];
    #pragma unroll
    for (int t = 0; t < 16; ++t) acc[t] = 0.f;
    #pragma unroll
    for (int k = 0; k < 8; ++k) {
      float4 xv = *(const float4*)(xp + k * 64);
      #pragma unroll
      for (int t = 0; t < 16; ++t) {
        float4 w4 = *(const float4*)&wl[t * 512 + k * 64 + sl * 4];
        acc[t] = fmaf(xv.x, w4.x, fmaf(xv.y, w4.y, fmaf(xv.z, w4.z, fmaf(xv.w, w4.w, acc[t]))));
      }
    }
    #pragma unroll
    for (int o = 1; o <= 8; o <<= 1)
      #pragma unroll
      for (int t = 0; t < 16; ++t) acc[t] += __shfl_xor(acc[t], o);
    float outv = acc[0];
    #pragma unroll
    for (int t = 1; t < 16; ++t) outv = (sl == t) ? acc[t] : outv;
    int h = sl >> 1;
    if (sl & 1) sj[(size_t)h * N + n] = outv;
    else        si[(size_t)h * N + n] = outv;
    return;
  }

  int wave = tid >> 6, lane = tid & 63;
  int r = lane & 15, q = lane >> 4;
  int wr = wave >> 1, wc = wave & 1;

  int blk = blockIdx.x;
  int mtile = blk % 80;               // 80 tiles of 128 rows (10240 padded)
  int head = blk / 80;                // blk%8 == mtile%8 -> XCD A-affinity
  int m0 = mtile * 128;
  int K8 = K >> 3;

  const bf16x8* pA = (const bf16x8*)Afh;
  const bf16x8* pB = (const bf16x8*)Bfh;
  size_t rstep = (size_t)K8 * 16;
  size_t aidx = (size_t)((m0 >> 4) + wr * 4) * rstep + (size_t)q * 16 + r;
  size_t bidx = (size_t)(head * 8 + wc * 4) * rstep + (size_t)q * 16 + r;

  f32x4 acc[4][4] = {};

  for (int k0 = 0; k0 < K; k0 += 128, aidx += 256, bidx += 256) {
    bf16x8 a[16], b[16];
    #pragma unroll
    for (int c = 0; c < 4; ++c)
      #pragma unroll
      for (int i = 0; i < 4; ++i) {
        a[c * 4 + i] = pA[aidx + i * rstep + c * 64];
        b[c * 4 + i] = pB[bidx + i * rstep + c * 64];
      }
    #pragma unroll
    for (int c = 0; c < 4; ++c)
      #pragma unroll
      for (int i = 0; i < 4; ++i)
        #pragma unroll
        for (int j = 0; j < 4; ++j)
          acc[i][j] = __builtin_amdgcn_mfma_f32_16x16x32_bf16(a[c * 4 + i], b[c * 4 + j], acc[i][j], 0, 0, 0);
  }

  // epilogue: C/D layout col = r, row = q*4 + reg (per 16x16 frag)
  #pragma unroll
  for (int i = 0; i < 4; ++i)
    #pragma unroll
    for (int reg = 0; reg < 4; ++reg) {
      int row = m0 + wr * 64 + i * 16 + q * 4 + reg;
      if (row < M) {
        #pragma unroll
        for (int j = 0; j < 4; ++j)
          hb[((size_t)head * M + row) * HID + wc * 64 + j * 16 + r] =
              f2bf_rne(acc[i][j][reg]);
      }
    }
}

// ---------------------------------------------------------------------------
// FUSED softmax + aggregation on the bucket CSR: one wave = FOUR dst nodes
// (16 lanes per dst) of one head.  8 row-gathers in flight; deg>32 tail
// scans the bounded overflow list.
// ---------------------------------------------------------------------------
__global__ __launch_bounds__(512)
void gat_aggregate9(const unsigned short* __restrict__ hb,
                    const float* __restrict__ si, const float* __restrict__ sj,
                    const int* __restrict__ deg, const int* __restrict__ slots,
                    const int2* __restrict__ ovf, const int* __restrict__ cnt,
                    unsigned short* __restrict__ aggb, int N) {
  __shared__ int2 prs[8][4][32];   // [wave][group][edge-slot] (src, w)
  int head = blockIdx.x & 7;
  int wv = threadIdx.x >> 6;
  int lane = threadIdx.x & 63;
  int grp = lane >> 4;
  int sl = lane & 15;
  int n = (blockIdx.x >> 3) * 32 + wv * 4 + grp;
  const unsigned short* hbase = hb + (size_t)head * N * HID;
  const float* sjh = sj + (size_t)head * N;
  bool nv = n < N;
  int dg = 0;
  float s_i = 0.f;
  if (nv) {
    dg = deg[n];
    s_i = si[(size_t)head * N + n];
  }
  int sbase = n * 32;

  // --- phase 1: per-lane edge scores, 2 slots (covers deg <= 32) ---
  int src0 = 0, src1 = 0;
  float sc0 = -INFINITY, sc1 = -INFINITY;
  if (sl < dg) {
    src0 = slots[sbase + sl];
    float t = s_i + sjh[src0];
    sc0 = t > 0.f ? t : 0.01f * t;
  }
  if (16 + sl < dg) {
    src1 = slots[sbase + 16 + sl];
    float t = s_i + sjh[src1];
    sc1 = t > 0.f ? t : 0.01f * t;
  }
  float m = fmaxf(sc0, sc1);
  int oc = 0;
  if (dg > 32) {                    // rare overflow tail: max
    oc = cnt[1];
    if (oc > N_EDGES) oc = N_EDGES; // defensive clamp
    for (int e2 = sl; e2 < oc; e2 += 16) {
      int2 pe = ovf[e2];
      if (pe.x == n) {
        float t = s_i + sjh[pe.y];
        t = t > 0.f ? t : 0.01f * t;
        m = fmaxf(m, t);
      }
    }
  }
  #pragma unroll
  for (int o = 1; o <= 8; o <<= 1) m = fmaxf(m, __shfl_xor(m, o));

  float w0 = (sl < dg) ? __expf(sc0 - m) : 0.f;
  float w1 = (16 + sl < dg) ? __expf(sc1 - m) : 0.f;
  float den = w0 + w1;
  if (dg > 32) {                    // rare overflow tail: denom
    for (int e2 = sl; e2 < oc; e2 += 16) {
      int2 pe = ovf[e2];
      if (pe.x == n) {
        float t = s_i + sjh[pe.y];
        t = t > 0.f ? t : 0.01f * t;
        den += __expf(t - m);
      }
    }
  }
  #pragma unroll
  for (int o = 1; o <= 8; o <<= 1) den += __shfl_xor(den, o);

  // stage pairs (w=0 beyond deg; src=0 -> safe dummy gather)
  prs[wv][grp][sl] = make_int2(src0, __float_as_int(w0));
  prs[wv][grp][16 + sl] = make_int2(src1, __float_as_int(w1));
  // wave-synchronous LDS: ensure writes land + block compiler reorder.
  __asm__ volatile("s_waitcnt lgkmcnt(0)" ::: "memory");

  // --- gather: 16 lanes cover the 128-dim row, 8 edges in flight ---
  v2f a01 = {0.f, 0.f}, a23 = {0.f, 0.f}, a45 = {0.f, 0.f}, a67 = {0.f, 0.f};
  int dmin = dg < 32 ? dg : 32;
  for (int e0 = 0; e0 < dmin; e0 += 8) {            // slots e0..e0+7 <= 31 always init'd
    int2 p[8];
    #pragma unroll
    for (int u = 0; u < 8; ++u) p[u] = prs[wv][grp][e0 + u];
    int4 pv[8];
    #pragma unroll
    for (int u = 0; u < 8; ++u)
      pv[u] = *(const int4*)&hbase[(size_t)p[u].x * HID + sl * 8];
    #pragma unroll
    for (int u = 0; u < 8; ++u) {
      float w = __int_as_float(p[u].y);
      v2f w2 = {w, w};
      int4 q = pv[u];
      v2f t0 = {bf2f((unsigned)q.x & 0xffffu), __uint_as_float((unsigned)q.x & 0xffff0000u)};
      v2f t1 = {bf2f((unsigned)q.y & 0xffffu), __uint_as_float((unsigned)q.y & 0xffff0000u)};
      v2f t2 = {bf2f((unsigned)q.z & 0xffffu), __uint_as_float((unsigned)q.z & 0xffff0000u)};
      v2f t3 = {bf2f((unsigned)q.w & 0xffffu), __uint_as_float((unsigned)q.w & 0xffff0000u)};
      a01 += w2 * t0;                 // v_pk_fma_f32
      a23 += w2 * t1;
      a45 += w2 * t2;
      a67 += w2 * t3;
    }
  }
  // rare tail: deg > 32, weights recomputed from the overflow list
  if (dg > 32) {
    for (int e2 = 0; e2 < oc; ++e2) {
      int2 pe = ovf[e2];
      if (pe.x != n) continue;
      float t = s_i + sjh[pe.y];
      t = t > 0.f ? t : 0.01f * t;
      float w = __expf(t - m);
      v2f w2 = {w, w};
      int4 q = *(const int4*)&hbase[(size_t)pe.y * HID + sl * 8];
      v2f t0 = {bf2f((unsigned)q.x & 0xffffu), __uint_as_float((unsigned)q.x & 0xffff0000u)};
      v2f t1 = {bf2f((unsigned)q.y & 0xffffu), __uint_as_float((unsigned)q.y & 0xffff0000u)};
      v2f t2 = {bf2f((unsigned)q.z & 0xffffu), __uint_as_float((unsigned)q.z & 0xffff0000u)};
      v2f t3 = {bf2f((unsigned)q.w & 0xffffu), __uint_as_float((unsigned)q.w & 0xffff0000u)};
      a01 += w2 * t0; a23 += w2 * t1; a45 += w2 * t2; a67 += w2 * t3;
    }
  }

  // --- epilogue: each lane owns 8 dims; all 64 lanes store ---
  if (nv) {
    float inv = den > 0.f ? 1.0f / den : 0.f;
    union { unsigned short u[8]; int4 v4; } P;
    P.u[0] = f2bf_rne(a01.x * inv); P.u[1] = f2bf_rne(a01.y * inv);
    P.u[2] = f2bf_rne(a23.x * inv); P.u[3] = f2bf_rne(a23.y * inv);
    P.u[4] = f2bf_rne(a45.x * inv); P.u[5] = f2bf_rne(a45.y * inv);
    P.u[6] = f2bf_rne(a67.x * inv); P.u[7] = f2bf_rne(a67.y * inv);
    *(int4*)&aggb[((size_t)head * N + n) * HID + sl * 8] = P.v4;
  }
}

// ---------------------------------------------------------------------------
// Head mean + ELU -> layer-2 A frags (bf16) + LAYER-2 SCORES (fp32 emb1 . wt2,
// block-complete reduction over the 16 col-chunks).
// ---------------------------------------------------------------------------
__global__ __launch_bounds__(256)
void headmean_frag2(const unsigned short* __restrict__ aggb,
                    unsigned short* __restrict__ hiA, int N,
                    const float* __restrict__ wt2,
                    float* __restrict__ si, float* __restrict__ sj) {
  __shared__ float wl[2048];              // wt2 [16 t][128 f], 8 KB
  __shared__ float sred[16][16][17];      // [kq][r][t] (+1 pad), 17.4 KB
  int tid = threadIdx.x;
  #pragma unroll
  for (int k = 0; k < 8; ++k) wl[tid + k * 256] = wt2[tid + k * 256];
  __syncthreads();
  int idx = blockIdx.x * 256 + tid;       // (rb,kq,r), K8=16
  int r = idx & 15;
  int kq = (idx >> 4) & 15;
  int rb = idx >> 8;
  int n = rb * 16 + r;
  float s[8] = {0.f, 0.f, 0.f, 0.f, 0.f, 0.f, 0.f, 0.f};
  if (n < N) {
    #pragma unroll
    for (int hh = 0; hh < HEADS; ++hh) {
      int4 pv = *(const int4*)&aggb[((size_t)hh * N + n) * HID + kq * 8];
      s[0] += bf2f((unsigned)pv.x & 0xffffu);
      s[1] += __uint_as_float((unsigned)pv.x & 0xffff0000u);
      s[2] += bf2f((unsigned)pv.y & 0xffffu);
      s[3] += __uint_as_float((unsigned)pv.y & 0xffff0000u);
      s[4] += bf2f((unsigned)pv.z & 0xffffu);
      s[5] += __uint_as_float((unsigned)pv.z & 0xffff0000u);
      s[6] += bf2f((unsigned)pv.w & 0xffffu);
      s[7] += __uint_as_float((unsigned)pv.w & 0xffff0000u);
    }
  }
  float p[16];
  #pragma unroll
  for (int t = 0; t < 16; ++t) p[t] = 0.f;
  union { unsigned short u[8]; int4 v4; } H;
  #pragma unroll
  for (int e = 0; e < 8; ++e) {
    float v = s[e] * (1.0f / HEADS);
    v = v > 0.f ? v : (__expf(v) - 1.0f);   // ELU (fp32 emb1)
    #pragma unroll
    for (int t = 0; t < 16; ++t) p[t] = fmaf(v, wl[t * 128 + kq * 8 + e], p[t]);
    H.u[e] = f2bf_rne(v);
  }
  *(int4*)&hiA[(size_t)idx * 8] = H.v4;
  #pragma unroll
  for (int t = 0; t < 16; ++t) sred[kq][r][t] = p[t];
  __syncthreads();
  {
    int rr = tid >> 4, t = tid & 15;
    float sum = 0.f;
    #pragma unroll
    for (int k = 0; k < 16; ++k) sum += sred[k][rr][t];
    int nn = rb * 16 + rr;
    if (nn < N) {
      int h = t >> 1;
      if (t & 1) sj[(size_t)h * N + nn] = sum;
      else       si[(size_t)h * N + nn] = sum;
    }
  }
}

// ---------------------------------------------------------------------------
// Layer-2 tail: head mean + ELU + graph pooling + (last block) LayerNorm+MLP.
// Last-block pattern: device-scope atomicAdd into g, threadfence, counter
// cnt[0] (re-zeroed by the in-stream memset each launch -> replay-safe);
// final block re-reads g via atomicAdd(p,0) (cross-XCD coherent).
// ---------------------------------------------------------------------------
__global__ __launch_bounds__(256)
void pool_mlp(const unsigned short* __restrict__ aggb, float* __restrict__ g,
              int N, int* __restrict__ cnt, int nbPool,
              const float* __restrict__ ln_g, const float* __restrict__ ln_b,
              const float* __restrict__ Wl1, const float* __restrict__ bl1,
              const float* __restrict__ Wl2, const float* __restrict__ bl2,
              const float* __restrict__ Wl3, const float* __restrict__ bl3,
              float* __restrict__ out, float invN) {
  __shared__ float sm[16][128];
  int t = threadIdx.x;
  int nl = t >> 4, dg = t & 15;
  int n = blockIdx.x * 16 + nl;
  float v[8] = {0.f, 0.f, 0.f, 0.f, 0.f, 0.f, 0.f, 0.f};
  if (n < N) {
    #pragma unroll
    for (int hh = 0; hh < HEADS; ++hh) {
      int4 pv = *(const int4*)&aggb[((size_t)hh * N + n) * HID + dg * 8];
      v[0] += bf2f((unsigned)pv.x & 0xffffu);
      v[1] += __uint_as_float((unsigned)pv.x & 0xffff0000u);
      v[2] += bf2f((unsigned)pv.y & 0xffffu);
      v[3] += __uint_as_float((unsigned)pv.y & 0xffff0000u);
      v[4] += bf2f((unsigned)pv.z & 0xffffu);
      v[5] += __uint_as_float((unsigned)pv.z & 0xffff0000u);
      v[6] += bf2f((unsigned)pv.w & 0xffffu);
      v[7] += __uint_as_float((unsigned)pv.w & 0xffff0000u);
    }
    #pragma unroll
    for (int e = 0; e < 8; ++e) {
      float x = v[e] * (1.0f / HEADS);
      v[e] = x > 0.f ? x : (__expf(x) - 1.0f);   // ELU
    }
  }
  #pragma unroll
  for (int e = 0; e < 8; ++e) sm[nl][dg * 8 + e] = v[e];
  __syncthreads();
  if (t < 128) {
    float s = 0.f;
    #pragma unroll
    for (int nn = 0; nn < 16; ++nn) s += sm[nn][t];
    atomicAdd(&g[t], s);
  }
  // ---- last block runs the MLP head ----
  __threadfence();
  __shared__ int lastFlag;
  if (t == 0) lastFlag = (atomicAdd(&cnt[0], 1) == nbPool - 1);
  __syncthreads();
  if (!lastFlag) return;

  __shared__ float red[128];
  __shared__ float gn[128];
  __shared__ float x1[64];
  __shared__ float x2[16];
  float gg = 0.f;
  if (t < 128) {
    gg = atomicAdd(&g[t], 0.f) * invN;     // coherent read of pooled sum
    red[t] = gg;
  }
  __syncthreads();
  for (int o = 64; o > 0; o >>= 1) {
    if (t < o) red[t] += red[t + o];
    __syncthreads();
  }
  float mu = red[0] * (1.0f / HID);
  __syncthreads();
  if (t < 128) {
    float dv = gg - mu;
    red[t] = dv * dv;
  }
  __syncthreads();
  for (int o = 64; o > 0; o >>= 1) {
    if (t < o) red[t] += red[t + o];
    __syncthreads();
  }
  float var = red[0] * (1.0f / HID);
  if (t < 128) gn[t] = (gg - mu) / sqrtf(var + 1e-5f) * ln_g[t] + ln_b[t];
  __syncthreads();
  if (t < 64) {
    float s = bl1[t];
    for (int k = 0; k < 128; ++k) s += Wl1[t * 128 + k] * gn[k];
    x1[t] = s > 0.f ? s : 0.01f * s;
  }
  __syncthreads();
  if (t < 16) {
    float s = bl2[t];
    for (int k = 0; k < 64; ++k) s += Wl2[t * 64 + k] * x1[k];
    x2[t] = s > 0.f ? s : 0.01f * s;
  }
  __syncthreads();
  if (t < 16) {
    float s = bl3[t];
    for (int k = 0; k < 16; ++k) s += Wl3[t * 16 + k] * x2[k];
    out[t] = s > 0.f ? s : 0.f;
  }
}

// ---------------------------------------------------------------------------
extern "C" void kernel_launch(void* const* d_in, const int* in_sizes, int n_in,
                              void* d_out, int out_size, void* d_ws, size_t ws_size,
                              hipStream_t stream) {
  const float* x    = (const float*)d_in[0];
  const int*   esrc = (const int*)d_in[1];
  const int*   edst = (const int*)d_in[2];
  const float* W1   = (const float*)d_in[3];
  const float* a1   = (const float*)d_in[4];
  const float* W2   = (const float*)d_in[5];
  const float* a2   = (const float*)d_in[6];
  const float* ln_g = (const float*)d_in[7];
  const float* ln_b = (const float*)d_in[8];
  const float* Wl1  = (const float*)d_in[9];
  const float* bl1  = (const float*)d_in[10];
  const float* Wl2  = (const float*)d_in[11];
  const float* bl2  = (const float*)d_in[12];
  const float* Wl3  = (const float*)d_in[13];
  const float* bl3  = (const float*)d_in[14];
  float* out = (float*)d_out;

  const int RBPAD = 640;  // row-blocks padded (10240 rows) for in-bounds frags

  // workspace carve-up (g, deg, cnt contiguous -> one memset)
  unsigned short* aggb = (unsigned short*)d_ws;                 // 20.5 MB
  float* si   = (float*)(aggb + (size_t)N_NODES * HEADS * HID); // 80,000
  float* sj   = si + N_NODES * HEADS;                           // 80,000
  float* g    = sj + N_NODES * HEADS;                           // 128
  int*   deg  = (int*)(g + 128);                                // 10,000
  int*   cnt  = deg + N_NODES;                                  // 4 (pool, ovf)
  int*   slots= cnt + 4;                                        // 320,000
  int2*  ovf  = (int2*)(slots + (size_t)N_NODES * 32);          // worst-case E
  float* wt1  = (float*)(ovf + N_EDGES);                        // 8192
  float* wt2  = wt1 + 8192;                                     // 2048
  unsigned short* Afh  = (unsigned short*)(wt2 + 2048);         // 10.5 MB
  unsigned short* Bfh  = Afh + (size_t)RBPAD * 64 * 128;        // W1 frags 1 MB
  unsigned short* Bfh2 = Bfh + (size_t)1024 * 512;              // W2 frags 256 KB
  unsigned short* hb   = Bfh2 + (size_t)1024 * 128;             // 20.5 MB

  // zero g + deg + cnt in ONE memset (contiguous)
  hipMemsetAsync(g, 0, 128 * sizeof(float) + (N_NODES + 4) * sizeof(int), stream);

  int gemmGrid = 80 * HEADS;                      // 640 blocks of 256 threads
  int scoreGrid = (N_NODES + 15) / 16;            // 625 score blocks
  int aggGrid = ((N_NODES + 31) / 32) * 8;        // 2504 blocks: 32 dst x 1 head

  // ---- ONE prep dispatch: A/W1/W2 splits + bucket CSR + wt1/wt2 ----
  {
    int totalA = RBPAD * 64 * 16;             // K8=64
    int nbA = (totalA + 255) / 256;           // 2560
    int totalB = 64 * 64 * 16;                // W1: 1024 rows, K8=64
    int nbB = (totalB + 255) / 256;           // 256
    int totalB2 = 64 * 16 * 16;               // W2: 1024 rows, K8=16
    int nbB2 = (totalB2 + 255) / 256;         // 64
    int nbE = (N_EDGES + 255) / 256;          // 625
    int nbW = 40;                             // 32 wt1 + 8 wt2
    split_frag2<<<nbA + nbB + nbB2 + nbE + nbW, 256, 0, stream>>>(
        x, Afh, N_NODES, 64, totalA, nbA,
        W1, Bfh, HEADS * HID, 64, totalB, nbB,
        W2, Bfh2, totalB2, nbB2,
        esrc, edst, deg, slots, ovf, cnt, N_EDGES,
        a1, a2, wt1, wt2);
  }

  // ---- Layer 1: GEMM + fused score GEMV in one dispatch ----
  gemm_score<<<gemmGrid + scoreGrid, 256, 0, stream>>>(
      Afh, Bfh, hb, N_NODES, N_FEAT, gemmGrid, x, wt1, si, sj, N_NODES);
  gat_aggregate9<<<aggGrid, 512, 0, stream>>>(hb, si, sj, deg, slots, ovf, cnt,
                                              aggb, N_NODES);
  headmean_frag2<<<(N_NODES + 15) / 16, 256, 0, stream>>>(aggb, Afh, N_NODES,
                                                          wt2, si, sj);

  // ---- Layer 2 ----
  gemm_score<<<gemmGrid, 256, 0, stream>>>(
      Afh, Bfh2, hb, N_NODES, HID, gemmGrid, nullptr, nullptr, nullptr, nullptr, 0);
  gat_aggregate9<<<aggGrid, 512, 0, stream>>>(hb, si, sj, deg, slots, ovf, cnt,
                                              aggb, N_NODES);

  // ---- fused head-mean + pooling + MLP head (last-block) ----
  {
    int nbPool = (N_NODES + 15) / 16;
    pool_mlp<<<nbPool, 256, 0, stream>>>(aggb, g, N_NODES, cnt, nbPool,
                                         ln_g, ln_b, Wl1, bl1, Wl2, bl2,
                                         Wl3, bl3, out, 1.0f / N_NODES);
  }
}

// Round 10
// 241.889 us; speedup vs baseline: 2.2300x; 1.1224x over previous
//
#include <hip/hip_runtime.h>
#include <math.h>

#define N_NODES 10000
#define N_EDGES 160000
#define N_FEAT  512
#define HEADS   8
#define HID     128

typedef __attribute__((ext_vector_type(8))) short bf16x8;
typedef __attribute__((ext_vector_type(4))) float f32x4;
typedef __attribute__((ext_vector_type(2))) float v2f;

// ---------------------------------------------------------------------------
// fp32 <-> bf16 helpers
// ---------------------------------------------------------------------------
__device__ inline unsigned short f2bf_rne(float f) {
  unsigned int u = __float_as_uint(f);
  unsigned int r = u + 0x7fffu + ((u >> 16) & 1u);
  return (unsigned short)(r >> 16);
}
__device__ inline float bf2f(unsigned int b) {
  return __uint_as_float(b << 16);
}

// ---------------------------------------------------------------------------
// split body: fp32 [R][K] -> bf16 in MFMA-fragment-major layout (hi only).
// ---------------------------------------------------------------------------
__device__ inline void split_body(const float* __restrict__ in,
                                  unsigned short* __restrict__ hi,
                                  int R, int K8, int idx) {
  int r = idx & 15;
  int t = idx >> 4;
  int kq = t % K8;
  int rb = t / K8;
  int row = rb * 16 + r;
  float v[8] = {0.f, 0.f, 0.f, 0.f, 0.f, 0.f, 0.f, 0.f};
  if (row < R) {
    const float* p = in + (size_t)row * (K8 * 8) + kq * 8;
    float4 a = *(const float4*)p;
    float4 b = *(const float4*)(p + 4);
    v[0] = a.x; v[1] = a.y; v[2] = a.z; v[3] = a.w;
    v[4] = b.x; v[5] = b.y; v[6] = b.z; v[7] = b.w;
  }
  union { unsigned short u[8]; int4 v4; } H;
  #pragma unroll
  for (int e = 0; e < 8; ++e) H.u[e] = f2bf_rne(v[e]);
  *(int4*)&hi[(size_t)idx * 8] = H.v4;
}

// ---------------------------------------------------------------------------
// ONE dispatch: A split + W1 split + W2 split + bucket-CSR build + w-tilde.
// Bucket CSR: slots[n][32] via atomicAdd(deg); overflow edges to a BOUNDED
// (dst,src) list scanned by the aggregate's rare tail (R6 hardening).
// ---------------------------------------------------------------------------
__global__ __launch_bounds__(256)
void split_frag2(const float* __restrict__ in1, unsigned short* __restrict__ hi1,
                 int R1, int K81, int total1, int nb1,
                 const float* __restrict__ in2, unsigned short* __restrict__ hi2,
                 int R2, int K82, int total2, int nb2,
                 const float* __restrict__ W2p, unsigned short* __restrict__ hi3,
                 int total3, int nb3,
                 const int* __restrict__ esrc, const int* __restrict__ edst,
                 int* __restrict__ deg, int* __restrict__ slots,
                 int2* __restrict__ ovf, int* __restrict__ cnt, int E,
                 const float* __restrict__ av1, const float* __restrict__ av2,
                 float* __restrict__ wt1, float* __restrict__ wt2) {
  int b = (int)blockIdx.x;
  int tid = threadIdx.x;
  if (b < nb1) {
    int idx = b * 256 + tid;
    if (idx < total1) split_body(in1, hi1, R1, K81, idx);
  } else if (b < nb1 + nb2) {
    int idx = (b - nb1) * 256 + tid;
    if (idx < total2) split_body(in2, hi2, R2, K82, idx);
  } else if (b < nb1 + nb2 + nb3) {
    int idx = (b - nb1 - nb2) * 256 + tid;
    if (idx < total3) split_body(W2p, hi3, HEADS * HID, 16, idx);
  } else {
    int nbE = (E + 255) / 256;
    int eb = b - nb1 - nb2 - nb3;
    if (eb < nbE) {
      int e = eb * 256 + tid;
      if (e < E) {
        int d = edst[e], s = esrc[e];
        int p = atomicAdd(&deg[d], 1);
        if (p < 32) {
          slots[d * 32 + p] = s;
        } else {
          int q = atomicAdd(&cnt[1], 1);
          if (q < E) ovf[q] = make_int2(d, s);   // bounded (defensive)
        }
      }
    } else {
      int wb = eb - nbE;
      if (wb < 32) {                      // wt1: 8192 outputs, 128-dots over W1
        int o = wb * 256 + tid;
        int f = o & 511, ii = (o >> 9) & 1, h = o >> 10;
        const float* Wp = in2 + (size_t)h * HID * N_FEAT + f;   // in2 == W1
        const float* ap = av1 + h * 2 * HID + ii * HID;
        float c0 = 0.f, c1 = 0.f;
        for (int d = 0; d < HID; d += 2) {
          c0 = fmaf(Wp[(size_t)d * N_FEAT], ap[d], c0);
          c1 = fmaf(Wp[(size_t)(d + 1) * N_FEAT], ap[d + 1], c1);
        }
        wt1[o] = c0 + c1;
      } else {                            // wt2: 2048 outputs over W2
        int o = (wb - 32) * 256 + tid;
        int f = o & 127, ii = (o >> 7) & 1, h = o >> 8;
        const float* Wp = W2p + (size_t)h * HID * HID + f;
        const float* ap = av2 + h * 2 * HID + ii * HID;
        float c0 = 0.f, c1 = 0.f;
        for (int d = 0; d < HID; d += 2) {
          c0 = fmaf(Wp[(size_t)d * HID], ap[d], c0);
          c1 = fmaf(Wp[(size_t)(d + 1) * HID], ap[d + 1], c1);
        }
        wt2[o] = c0 + c1;
      }
    }
  }
}

// ---------------------------------------------------------------------------
// Pure-bf16 MFMA GEMM (128x128 tile, 2x2 waves) + FUSED layer-1 score GEMV.
// BK=128 (K=512 -> 4 iterations): gemm law from R2/R3/R9 — time ~ number of
// load-latency exposures, not per-iter work (R9 accounting: BK 64->128 was
// ~ -6us).  launch_bounds(256,2) gives the allocator the 256-VGPR budget
// (R8 lesson: starving it spills catastrophically).
// ---------------------------------------------------------------------------
__global__ __launch_bounds__(256, 2)
void gemm_score(const unsigned short* __restrict__ Afh,
                const unsigned short* __restrict__ Bfh,
                unsigned short* __restrict__ hb,
                int M, int K, int nbGemm,
                const float* __restrict__ x, const float* __restrict__ wt1,
                float* __restrict__ si, float* __restrict__ sj, int N) {
  int tid = threadIdx.x;
  if ((int)blockIdx.x >= nbGemm) {
    // ---- score blocks: 16 rows each; wave = 4 rows x 16 lanes ----
    __shared__ float wl[8192];            // wt1 [16 t][512 f], 32 KB
    #pragma unroll
    for (int k = 0; k < 32; ++k) wl[tid + k * 256] = wt1[tid + k * 256];
    __syncthreads();
    int wv = tid >> 6, lane = tid & 63;
    int rr = lane >> 4, sl = lane & 15;
    int n = ((int)blockIdx.x - nbGemm) * 16 + wv * 4 + rr;
    if (n >= N) return;
    const float* xp = x + (size_t)n * N_FEAT + sl * 4;
    float acc[16];
    #pragma unroll
    for (int t = 0; t < 16; ++t) acc[t] = 0.f;
    #pragma unroll
    for (int k = 0; k < 8; ++k) {
      float4 xv = *(const float4*)(xp + k * 64);
      #pragma unroll
      for (int t = 0; t < 16; ++t) {
        float4 w4 = *(const float4*)&wl[t * 512 + k * 64 + sl * 4];
        acc[t] = fmaf(xv.x, w4.x, fmaf(xv.y, w4.y, fmaf(xv.z, w4.z, fmaf(xv.w, w4.w, acc[t]))));
      }
    }
    #pragma unroll
    for (int o = 1; o <= 8; o <<= 1)
      #pragma unroll
      for (int t = 0; t < 16; ++t) acc[t] += __shfl_xor(acc[t], o);
    float outv = acc[0];
    #pragma unroll
    for (int t = 1; t < 16; ++t) outv = (sl == t) ? acc[t] : outv;
    int h = sl >> 1;
    if (sl & 1) sj[(size_t)h * N + n] = outv;
    else        si[(size_t)h * N + n] = outv;
    return;
  }

  int wave = tid >> 6, lane = tid & 63;
  int r = lane & 15, q = lane >> 4;
  int wr = wave >> 1, wc = wave & 1;

  int blk = blockIdx.x;
  int mtile = blk % 80;               // 80 tiles of 128 rows (10240 padded)
  int head = blk / 80;                // blk%8 == mtile%8 -> XCD A-affinity
  int m0 = mtile * 128;
  int K8 = K >> 3;

  const bf16x8* pA = (const bf16x8*)Afh;
  const bf16x8* pB = (const bf16x8*)Bfh;
  size_t rstep = (size_t)K8 * 16;
  size_t aidx = (size_t)((m0 >> 4) + wr * 4) * rstep + (size_t)q * 16 + r;
  size_t bidx = (size_t)(head * 8 + wc * 4) * rstep + (size_t)q * 16 + r;

  f32x4 acc[4][4] = {};

  for (int k0 = 0; k0 < K; k0 += 128, aidx += 256, bidx += 256) {
    bf16x8 a[16], b[16];
    #pragma unroll
    for (int c = 0; c < 4; ++c)
      #pragma unroll
      for (int i = 0; i < 4; ++i) {
        a[c * 4 + i] = pA[aidx + i * rstep + c * 64];
        b[c * 4 + i] = pB[bidx + i * rstep + c * 64];
      }
    #pragma unroll
    for (int c = 0; c < 4; ++c)
      #pragma unroll
      for (int i = 0; i < 4; ++i)
        #pragma unroll
        for (int j = 0; j < 4; ++j)
          acc[i][j] = __builtin_amdgcn_mfma_f32_16x16x32_bf16(a[c * 4 + i], b[c * 4 + j], acc[i][j], 0, 0, 0);
  }

  // epilogue: C/D layout col = r, row = q*4 + reg (per 16x16 frag)
  #pragma unroll
  for (int i = 0; i < 4; ++i)
    #pragma unroll
    for (int reg = 0; reg < 4; ++reg) {
      int row = m0 + wr * 64 + i * 16 + q * 4 + reg;
      if (row < M) {
        #pragma unroll
        for (int j = 0; j < 4; ++j)
          hb[((size_t)head * M + row) * HID + wc * 64 + j * 16 + r] =
              f2bf_rne(acc[i][j][reg]);
      }
    }
}

// ---------------------------------------------------------------------------
// FUSED softmax + aggregation on the bucket CSR: one wave = FOUR dst nodes
// (16 lanes per dst) of one head.  8 row-gathers in flight; deg>32 tail
// scans the bounded overflow list.
// ---------------------------------------------------------------------------
__global__ __launch_bounds__(512)
void gat_aggregate9(const unsigned short* __restrict__ hb,
                    const float* __restrict__ si, const float* __restrict__ sj,
                    const int* __restrict__ deg, const int* __restrict__ slots,
                    const int2* __restrict__ ovf, const int* __restrict__ cnt,
                    unsigned short* __restrict__ aggb, int N) {
  __shared__ int2 prs[8][4][32];   // [wave][group][edge-slot] (src, w)
  int head = blockIdx.x & 7;
  int wv = threadIdx.x >> 6;
  int lane = threadIdx.x & 63;
  int grp = lane >> 4;
  int sl = lane & 15;
  int n = (blockIdx.x >> 3) * 32 + wv * 4 + grp;
  const unsigned short* hbase = hb + (size_t)head * N * HID;
  const float* sjh = sj + (size_t)head * N;
  bool nv = n < N;
  int dg = 0;
  float s_i = 0.f;
  if (nv) {
    dg = deg[n];
    s_i = si[(size_t)head * N + n];
  }
  int sbase = n * 32;

  // --- phase 1: per-lane edge scores, 2 slots (covers deg <= 32) ---
  int src0 = 0, src1 = 0;
  float sc0 = -INFINITY, sc1 = -INFINITY;
  if (sl < dg) {
    src0 = slots[sbase + sl];
    float t = s_i + sjh[src0];
    sc0 = t > 0.f ? t : 0.01f * t;
  }
  if (16 + sl < dg) {
    src1 = slots[sbase + 16 + sl];
    float t = s_i + sjh[src1];
    sc1 = t > 0.f ? t : 0.01f * t;
  }
  float m = fmaxf(sc0, sc1);
  int oc = 0;
  if (dg > 32) {                    // rare overflow tail: max
    oc = cnt[1];
    if (oc > N_EDGES) oc = N_EDGES; // defensive clamp
    for (int e2 = sl; e2 < oc; e2 += 16) {
      int2 pe = ovf[e2];
      if (pe.x == n) {
        float t = s_i + sjh[pe.y];
        t = t > 0.f ? t : 0.01f * t;
        m = fmaxf(m, t);
      }
    }
  }
  #pragma unroll
  for (int o = 1; o <= 8; o <<= 1) m = fmaxf(m, __shfl_xor(m, o));

  float w0 = (sl < dg) ? __expf(sc0 - m) : 0.f;
  float w1 = (16 + sl < dg) ? __expf(sc1 - m) : 0.f;
  float den = w0 + w1;
  if (dg > 32) {                    // rare overflow tail: denom
    for (int e2 = sl; e2 < oc; e2 += 16) {
      int2 pe = ovf[e2];
      if (pe.x == n) {
        float t = s_i + sjh[pe.y];
        t = t > 0.f ? t : 0.01f * t;
        den += __expf(t - m);
      }
    }
  }
  #pragma unroll
  for (int o = 1; o <= 8; o <<= 1) den += __shfl_xor(den, o);

  // stage pairs (w=0 beyond deg; src=0 -> safe dummy gather)
  prs[wv][grp][sl] = make_int2(src0, __float_as_int(w0));
  prs[wv][grp][16 + sl] = make_int2(src1, __float_as_int(w1));
  // wave-synchronous LDS: ensure writes land + block compiler reorder.
  __asm__ volatile("s_waitcnt lgkmcnt(0)" ::: "memory");

  // --- gather: 16 lanes cover the 128-dim row, 8 edges in flight ---
  v2f a01 = {0.f, 0.f}, a23 = {0.f, 0.f}, a45 = {0.f, 0.f}, a67 = {0.f, 0.f};
  int dmin = dg < 32 ? dg : 32;
  for (int e0 = 0; e0 < dmin; e0 += 8) {            // slots e0..e0+7 <= 31 always init'd
    int2 p[8];
    #pragma unroll
    for (int u = 0; u < 8; ++u) p[u] = prs[wv][grp][e0 + u];
    int4 pv[8];
    #pragma unroll
    for (int u = 0; u < 8; ++u)
      pv[u] = *(const int4*)&hbase[(size_t)p[u].x * HID + sl * 8];
    #pragma unroll
    for (int u = 0; u < 8; ++u) {
      float w = __int_as_float(p[u].y);
      v2f w2 = {w, w};
      int4 q = pv[u];
      v2f t0 = {bf2f((unsigned)q.x & 0xffffu), __uint_as_float((unsigned)q.x & 0xffff0000u)};
      v2f t1 = {bf2f((unsigned)q.y & 0xffffu), __uint_as_float((unsigned)q.y & 0xffff0000u)};
      v2f t2 = {bf2f((unsigned)q.z & 0xffffu), __uint_as_float((unsigned)q.z & 0xffff0000u)};
      v2f t3 = {bf2f((unsigned)q.w & 0xffffu), __uint_as_float((unsigned)q.w & 0xffff0000u)};
      a01 += w2 * t0;                 // v_pk_fma_f32
      a23 += w2 * t1;
      a45 += w2 * t2;
      a67 += w2 * t3;
    }
  }
  // rare tail: deg > 32, weights recomputed from the overflow list
  if (dg > 32) {
    for (int e2 = 0; e2 < oc; ++e2) {
      int2 pe = ovf[e2];
      if (pe.x != n) continue;
      float t = s_i + sjh[pe.y];
      t = t > 0.f ? t : 0.01f * t;
      float w = __expf(t - m);
      v2f w2 = {w, w};
      int4 q = *(const int4*)&hbase[(size_t)pe.y * HID + sl * 8];
      v2f t0 = {bf2f((unsigned)q.x & 0xffffu), __uint_as_float((unsigned)q.x & 0xffff0000u)};
      v2f t1 = {bf2f((unsigned)q.y & 0xffffu), __uint_as_float((unsigned)q.y & 0xffff0000u)};
      v2f t2 = {bf2f((unsigned)q.z & 0xffffu), __uint_as_float((unsigned)q.z & 0xffff0000u)};
      v2f t3 = {bf2f((unsigned)q.w & 0xffffu), __uint_as_float((unsigned)q.w & 0xffff0000u)};
      a01 += w2 * t0; a23 += w2 * t1; a45 += w2 * t2; a67 += w2 * t3;
    }
  }

  // --- epilogue: each lane owns 8 dims; all 64 lanes store ---
  if (nv) {
    float inv = den > 0.f ? 1.0f / den : 0.f;
    union { unsigned short u[8]; int4 v4; } P;
    P.u[0] = f2bf_rne(a01.x * inv); P.u[1] = f2bf_rne(a01.y * inv);
    P.u[2] = f2bf_rne(a23.x * inv); P.u[3] = f2bf_rne(a23.y * inv);
    P.u[4] = f2bf_rne(a45.x * inv); P.u[5] = f2bf_rne(a45.y * inv);
    P.u[6] = f2bf_rne(a67.x * inv); P.u[7] = f2bf_rne(a67.y * inv);
    *(int4*)&aggb[((size_t)head * N + n) * HID + sl * 8] = P.v4;
  }
}

// ---------------------------------------------------------------------------
// Head mean + ELU -> layer-2 A frags (bf16) + LAYER-2 SCORES (fp32 emb1 . wt2,
// block-complete reduction over the 16 col-chunks).
// ---------------------------------------------------------------------------
__global__ __launch_bounds__(256)
void headmean_frag2(const unsigned short* __restrict__ aggb,
                    unsigned short* __restrict__ hiA, int N,
                    const float* __restrict__ wt2,
                    float* __restrict__ si, float* __restrict__ sj) {
  __shared__ float wl[2048];              // wt2 [16 t][128 f], 8 KB
  __shared__ float sred[16][16][17];      // [kq][r][t] (+1 pad), 17.4 KB
  int tid = threadIdx.x;
  #pragma unroll
  for (int k = 0; k < 8; ++k) wl[tid + k * 256] = wt2[tid + k * 256];
  __syncthreads();
  int idx = blockIdx.x * 256 + tid;       // (rb,kq,r), K8=16
  int r = idx & 15;
  int kq = (idx >> 4) & 15;
  int rb = idx >> 8;
  int n = rb * 16 + r;
  float s[8] = {0.f, 0.f, 0.f, 0.f, 0.f, 0.f, 0.f, 0.f};
  if (n < N) {
    #pragma unroll
    for (int hh = 0; hh < HEADS; ++hh) {
      int4 pv = *(const int4*)&aggb[((size_t)hh * N + n) * HID + kq * 8];
      s[0] += bf2f((unsigned)pv.x & 0xffffu);
      s[1] += __uint_as_float((unsigned)pv.x & 0xffff0000u);
      s[2] += bf2f((unsigned)pv.y & 0xffffu);
      s[3] += __uint_as_float((unsigned)pv.y & 0xffff0000u);
      s[4] += bf2f((unsigned)pv.z & 0xffffu);
      s[5] += __uint_as_float((unsigned)pv.z & 0xffff0000u);
      s[6] += bf2f((unsigned)pv.w & 0xffffu);
      s[7] += __uint_as_float((unsigned)pv.w & 0xffff0000u);
    }
  }
  float p[16];
  #pragma unroll
  for (int t = 0; t < 16; ++t) p[t] = 0.f;
  union { unsigned short u[8]; int4 v4; } H;
  #pragma unroll
  for (int e = 0; e < 8; ++e) {
    float v = s[e] * (1.0f / HEADS);
    v = v > 0.f ? v : (__expf(v) - 1.0f);   // ELU (fp32 emb1)
    #pragma unroll
    for (int t = 0; t < 16; ++t) p[t] = fmaf(v, wl[t * 128 + kq * 8 + e], p[t]);
    H.u[e] = f2bf_rne(v);
  }
  *(int4*)&hiA[(size_t)idx * 8] = H.v4;
  #pragma unroll
  for (int t = 0; t < 16; ++t) sred[kq][r][t] = p[t];
  __syncthreads();
  {
    int rr = tid >> 4, t = tid & 15;
    float sum = 0.f;
    #pragma unroll
    for (int k = 0; k < 16; ++k) sum += sred[k][rr][t];
    int nn = rb * 16 + rr;
    if (nn < N) {
      int h = t >> 1;
      if (t & 1) sj[(size_t)h * N + nn] = sum;
      else       si[(size_t)h * N + nn] = sum;
    }
  }
}

// ---------------------------------------------------------------------------
// Layer-2 tail: head mean + ELU + graph pooling (R7-proven separate dispatch;
// R9's last-block fusion cost ~35us: 625 device-scope threadfences serialize
// L2 writebacks across the 8 non-coherent XCDs).
// ---------------------------------------------------------------------------
__global__ __launch_bounds__(256)
void headmean_pool(const unsigned short* __restrict__ aggb, float* __restrict__ g,
                   int N) {
  __shared__ float sm[16][128];
  int t = threadIdx.x;
  int nl = t >> 4, dg = t & 15;
  int n = blockIdx.x * 16 + nl;
  float v[8] = {0.f, 0.f, 0.f, 0.f, 0.f, 0.f, 0.f, 0.f};
  if (n < N) {
    #pragma unroll
    for (int hh = 0; hh < HEADS; ++hh) {
      int4 pv = *(const int4*)&aggb[((size_t)hh * N + n) * HID + dg * 8];
      v[0] += bf2f((unsigned)pv.x & 0xffffu);
      v[1] += __uint_as_float((unsigned)pv.x & 0xffff0000u);
      v[2] += bf2f((unsigned)pv.y & 0xffffu);
      v[3] += __uint_as_float((unsigned)pv.y & 0xffff0000u);
      v[4] += bf2f((unsigned)pv.z & 0xffffu);
      v[5] += __uint_as_float((unsigned)pv.z & 0xffff0000u);
      v[6] += bf2f((unsigned)pv.w & 0xffffu);
      v[7] += __uint_as_float((unsigned)pv.w & 0xffff0000u);
    }
    #pragma unroll
    for (int e = 0; e < 8; ++e) {
      float x = v[e] * (1.0f / HEADS);
      v[e] = x > 0.f ? x : (__expf(x) - 1.0f);   // ELU
    }
  }
  #pragma unroll
  for (int e = 0; e < 8; ++e) sm[nl][dg * 8 + e] = v[e];
  __syncthreads();
  if (t < 128) {
    float s = 0.f;
    #pragma unroll
    for (int nn = 0; nn < 16; ++nn) s += sm[nn][t];
    atomicAdd(&g[t], s);
  }
}

// ---------------------------------------------------------------------------
// LayerNorm + MLP head
// ---------------------------------------------------------------------------
__global__ __launch_bounds__(128)
void mlp_kernel(const float* __restrict__ g, const float* __restrict__ ln_g,
                const float* __restrict__ ln_b, const float* __restrict__ Wl1,
                const float* __restrict__ bl1, const float* __restrict__ Wl2,
                const float* __restrict__ bl2, const float* __restrict__ Wl3,
                const float* __restrict__ bl3, float* __restrict__ out, float invN) {
  __shared__ float red[128];
  __shared__ float gn[128];
  __shared__ float x1[64];
  __shared__ float x2[16];
  int t = threadIdx.x;
  float gg = g[t] * invN;
  red[t] = gg;
  __syncthreads();
  for (int o = 64; o > 0; o >>= 1) {
    if (t < o) red[t] += red[t + o];
    __syncthreads();
  }
  float mu = red[0] * (1.0f / HID);
  __syncthreads();
  float dv = gg - mu;
  red[t] = dv * dv;
  __syncthreads();
  for (int o = 64; o > 0; o >>= 1) {
    if (t < o) red[t] += red[t + o];
    __syncthreads();
  }
  float var = red[0] * (1.0f / HID);
  gn[t] = dv / sqrtf(var + 1e-5f) * ln_g[t] + ln_b[t];
  __syncthreads();
  if (t < 64) {
    float s = bl1[t];
    for (int k = 0; k < 128; ++k) s += Wl1[t * 128 + k] * gn[k];
    x1[t] = s > 0.f ? s : 0.01f * s;
  }
  __syncthreads();
  if (t < 16) {
    float s = bl2[t];
    for (int k = 0; k < 64; ++k) s += Wl2[t * 64 + k] * x1[k];
    x2[t] = s > 0.f ? s : 0.01f * s;
  }
  __syncthreads();
  if (t < 16) {
    float s = bl3[t];
    for (int k = 0; k < 16; ++k) s += Wl3[t * 16 + k] * x2[k];
    out[t] = s > 0.f ? s : 0.f;
  }
}

// ---------------------------------------------------------------------------
extern "C" void kernel_launch(void* const* d_in, const int* in_sizes, int n_in,
                              void* d_out, int out_size, void* d_ws, size_t ws_size,
                              hipStream_t stream) {
  const float* x    = (const float*)d_in[0];
  const int*   esrc = (const int*)d_in[1];
  const int*   edst = (const int*)d_in[2];
  const float* W1   = (const float*)d_in[3];
  const float* a1   = (const float*)d_in[4];
  const float* W2   = (const float*)d_in[5];
  const float* a2   = (const float*)d_in[6];
  const float* ln_g = (const float*)d_in[7];
  const float* ln_b = (const float*)d_in[8];
  const float* Wl1  = (const float*)d_in[9];
  const float* bl1  = (const float*)d_in[10];
  const float* Wl2  = (const float*)d_in[11];
  const float* bl2  = (const float*)d_in[12];
  const float* Wl3  = (const float*)d_in[13];
  const float* bl3  = (const float*)d_in[14];
  float* out = (float*)d_out;

  const int RBPAD = 640;  // row-blocks padded (10240 rows) for in-bounds frags

  // workspace carve-up (g, deg, cnt contiguous -> one memset)
  unsigned short* aggb = (unsigned short*)d_ws;                 // 20.5 MB
  float* si   = (float*)(aggb + (size_t)N_NODES * HEADS * HID); // 80,000
  float* sj   = si + N_NODES * HEADS;                           // 80,000
  float* g    = sj + N_NODES * HEADS;                           // 128
  int*   deg  = (int*)(g + 128);                                // 10,000
  int*   cnt  = deg + N_NODES;                                  // 4 (spare, ovf)
  int*   slots= cnt + 4;                                        // 320,000
  int2*  ovf  = (int2*)(slots + (size_t)N_NODES * 32);          // worst-case E
  float* wt1  = (float*)(ovf + N_EDGES);                        // 8192
  float* wt2  = wt1 + 8192;                                     // 2048
  unsigned short* Afh  = (unsigned short*)(wt2 + 2048);         // 10.5 MB
  unsigned short* Bfh  = Afh + (size_t)RBPAD * 64 * 128;        // W1 frags 1 MB
  unsigned short* Bfh2 = Bfh + (size_t)1024 * 512;              // W2 frags 256 KB
  unsigned short* hb   = Bfh2 + (size_t)1024 * 128;             // 20.5 MB

  // zero g + deg + cnt in ONE memset (contiguous)
  hipMemsetAsync(g, 0, 128 * sizeof(float) + (N_NODES + 4) * sizeof(int), stream);

  int gemmGrid = 80 * HEADS;                      // 640 blocks of 256 threads
  int scoreGrid = (N_NODES + 15) / 16;            // 625 score blocks
  int aggGrid = ((N_NODES + 31) / 32) * 8;        // 2504 blocks: 32 dst x 1 head

  // ---- ONE prep dispatch: A/W1/W2 splits + bucket CSR + wt1/wt2 ----
  {
    int totalA = RBPAD * 64 * 16;             // K8=64
    int nbA = (totalA + 255) / 256;           // 2560
    int totalB = 64 * 64 * 16;                // W1: 1024 rows, K8=64
    int nbB = (totalB + 255) / 256;           // 256
    int totalB2 = 64 * 16 * 16;               // W2: 1024 rows, K8=16
    int nbB2 = (totalB2 + 255) / 256;         // 64
    int nbE = (N_EDGES + 255) / 256;          // 625
    int nbW = 40;                             // 32 wt1 + 8 wt2
    split_frag2<<<nbA + nbB + nbB2 + nbE + nbW, 256, 0, stream>>>(
        x, Afh, N_NODES, 64, totalA, nbA,
        W1, Bfh, HEADS * HID, 64, totalB, nbB,
        W2, Bfh2, totalB2, nbB2,
        esrc, edst, deg, slots, ovf, cnt, N_EDGES,
        a1, a2, wt1, wt2);
  }

  // ---- Layer 1: GEMM + fused score GEMV in one dispatch ----
  gemm_score<<<gemmGrid + scoreGrid, 256, 0, stream>>>(
      Afh, Bfh, hb, N_NODES, N_FEAT, gemmGrid, x, wt1, si, sj, N_NODES);
  gat_aggregate9<<<aggGrid, 512, 0, stream>>>(hb, si, sj, deg, slots, ovf, cnt,
                                              aggb, N_NODES);
  headmean_frag2<<<(N_NODES + 15) / 16, 256, 0, stream>>>(aggb, Afh, N_NODES,
                                                          wt2, si, sj);

  // ---- Layer 2 ----
  gemm_score<<<gemmGrid, 256, 0, stream>>>(
      Afh, Bfh2, hb, N_NODES, HID, gemmGrid, nullptr, nullptr, nullptr, nullptr, 0);
  gat_aggregate9<<<aggGrid, 512, 0, stream>>>(hb, si, sj, deg, slots, ovf, cnt,
                                              aggb, N_NODES);

  // ---- head-mean + pooling, then MLP head ----
  headmean_pool<<<(N_NODES + 15) / 16, 256, 0, stream>>>(aggb, g, N_NODES);
  mlp_kernel<<<1, 128, 0, stream>>>(g, ln_g, ln_b, Wl1, bl1, Wl2, bl2, Wl3, bl3,
                                    out, 1.0f / N_NODES);
}